// Round 10
// baseline (253.373 us; speedup 1.0000x reference)
//
#include <hip/hip_runtime.h>

#define NN 200000
#define NE 3200000
#define NB_SCAN 782    // ceil(NN/256) node-scan blocks
#define NBUCK 196      // dst buckets of 1024 nodes (dst>>10)
#define BSHIFT 10
#define BMASK 1023
#define SRCMASK 0x3FFFFu   // src fits in 18 bits (200000 < 2^18)
#define NBLK_A 512     // bucket-pass blocks
#define EPB (NE / NBLK_A)  // 6250 edges per bucket-pass block
#define NT_MLP1 12500  // NN/16 wave-tiles

using bf16x8 = __attribute__((ext_vector_type(8))) short;
using f32x4  = __attribute__((ext_vector_type(4))) float;

__device__ __forceinline__ float bflo(unsigned u) { return __uint_as_float(u << 16); }
__device__ __forceinline__ float bfhi(unsigned u) { return __uint_as_float(u & 0xffff0000u); }
__device__ __forceinline__ unsigned short f2bfu(float f) {
  unsigned u = __float_as_uint(f);
  return (unsigned short)((u + 0x7fffu + ((u >> 16) & 1u)) >> 16);  // RNE
}
__device__ __forceinline__ unsigned pack2(float a, float b) {
  return (unsigned)f2bfu(a) | ((unsigned)f2bfu(b) << 16);
}

// ======================= stage 1: bucket histogram (LDS) =======================

__global__ __launch_bounds__(256) void bhist_kernel(const int* __restrict__ dst,
                                                    int* __restrict__ bhT) {
  __shared__ int h[NBUCK];
  for (int k = threadIdx.x; k < NBUCK; k += 256) h[k] = 0;
  __syncthreads();
  int base = blockIdx.x * EPB;
  for (int i = threadIdx.x; i < EPB; i += 256)
    atomicAdd(&h[dst[base + i] >> BSHIFT], 1);
  __syncthreads();
  for (int k = threadIdx.x; k < NBUCK; k += 256)
    bhT[k * NBLK_A + blockIdx.x] = h[k];
}

// per-bucket exclusive scan over the NBLK_A block entries -> bhT in place, totals
__global__ __launch_bounds__(NBLK_A) void bscan_kernel(int* __restrict__ bhT,
                                                       int* __restrict__ btot) {
  __shared__ int s[NBLK_A];
  int b = blockIdx.x;
  int v = bhT[b * NBLK_A + threadIdx.x];
  s[threadIdx.x] = v;
  __syncthreads();
#pragma unroll
  for (int off = 1; off < NBLK_A; off <<= 1) {
    int t = (threadIdx.x >= off) ? s[threadIdx.x - off] : 0;
    __syncthreads();
    s[threadIdx.x] += t;
    __syncthreads();
  }
  bhT[b * NBLK_A + threadIdx.x] = s[threadIdx.x] - v;  // exclusive
  if (threadIdx.x == NBLK_A - 1) btot[b] = s[NBLK_A - 1];
}

// exclusive scan of btot[NBUCK] -> bbase[NBUCK+1]
__global__ __launch_bounds__(256) void bbase_kernel(const int* __restrict__ btot,
                                                    int* __restrict__ bbase) {
  __shared__ int s[256];
  int v = (threadIdx.x < NBUCK) ? btot[threadIdx.x] : 0;
  s[threadIdx.x] = v;
  __syncthreads();
#pragma unroll
  for (int off = 1; off < 256; off <<= 1) {
    int t = (threadIdx.x >= off) ? s[threadIdx.x - off] : 0;
    __syncthreads();
    s[threadIdx.x] += t;
    __syncthreads();
  }
  if (threadIdx.x < NBUCK) bbase[threadIdx.x] = s[threadIdx.x] - v;
  if (threadIdx.x == NBUCK - 1) bbase[NBUCK] = s[threadIdx.x];
}

// bucket placement: write packed edge {src | dst_lo<<18, kw2} bucket-sorted
__global__ __launch_bounds__(256) void bplace_kernel(
    const int* __restrict__ src, const int* __restrict__ dst,
    const float* __restrict__ kw, const int* __restrict__ bhT,
    const int* __restrict__ bbase, uint2* __restrict__ bsorted) {
  __shared__ int cur[NBUCK];
  for (int k = threadIdx.x; k < NBUCK; k += 256)
    cur[k] = bbase[k] + bhT[k * NBLK_A + blockIdx.x];
  __syncthreads();
  int base = blockIdx.x * EPB;
  for (int i = threadIdx.x; i < EPB; i += 256) {
    int e = base + i;
    int d = dst[e];
    int p = atomicAdd(&cur[d >> BSHIFT], 1);
    uint2 u;
    u.x = (unsigned)src[e] | ((unsigned)(d & BMASK) << 18);
    u.y = pack2(kw[e], kw[NE + e]);
    bsorted[p] = u;
  }
}

// ======================= stage 2: per-node counts (LDS) =======================

__global__ __launch_bounds__(1024) void nhist_kernel(const uint2* __restrict__ bsorted,
                                                     const int* __restrict__ bbase,
                                                     int* __restrict__ cnt) {
  __shared__ int h[1024];
  h[threadIdx.x] = 0;
  __syncthreads();
  int b = blockIdx.x;
  int r0 = bbase[b], r1 = bbase[b + 1];
  for (int i = r0 + threadIdx.x; i < r1; i += 1024)
    atomicAdd(&h[bsorted[i].x >> 18], 1);
  __syncthreads();
  int node = b * 1024 + threadIdx.x;
  if (node < NN) cnt[node] = h[threadIdx.x];
}

// node-level scans (global exclusive offsets)
__global__ __launch_bounds__(256) void scan1_kernel(const int* __restrict__ cnt,
                                                    int* __restrict__ offs,
                                                    int* __restrict__ bsums) {
  __shared__ int s[256];
  int i = blockIdx.x * 256 + threadIdx.x;
  int v = (i < NN) ? cnt[i] : 0;
  s[threadIdx.x] = v;
  __syncthreads();
#pragma unroll
  for (int off = 1; off < 256; off <<= 1) {
    int t = (threadIdx.x >= off) ? s[threadIdx.x - off] : 0;
    __syncthreads();
    s[threadIdx.x] += t;
    __syncthreads();
  }
  if (i < NN) offs[i] = s[threadIdx.x];
  if (threadIdx.x == 255) bsums[blockIdx.x] = s[255];
}

__global__ __launch_bounds__(1024) void scan2_kernel(int* __restrict__ bsums, int nb) {
  __shared__ int s[1024];
  int v = (threadIdx.x < nb) ? bsums[threadIdx.x] : 0;
  s[threadIdx.x] = v;
  __syncthreads();
#pragma unroll
  for (int off = 1; off < 1024; off <<= 1) {
    int t = (threadIdx.x >= off) ? s[threadIdx.x - off] : 0;
    __syncthreads();
    s[threadIdx.x] += t;
    __syncthreads();
  }
  if (threadIdx.x < nb) bsums[threadIdx.x] = s[threadIdx.x] - v;  // exclusive
}

__global__ __launch_bounds__(256) void scan3_kernel(const int* __restrict__ cnt,
                                                    const int* __restrict__ bsums,
                                                    int* __restrict__ offs) {
  int i = blockIdx.x * 256 + threadIdx.x;
  if (i >= NN) return;
  offs[i] = offs[i] - cnt[i] + bsums[blockIdx.x];
}

// final placement within bucket window (L2-resident writes)
__global__ __launch_bounds__(1024) void nplace_kernel(const uint2* __restrict__ bsorted,
                                                      const int* __restrict__ bbase,
                                                      const int* __restrict__ offs,
                                                      uint2* __restrict__ sedge) {
  __shared__ int cur[1024];
  int b = blockIdx.x;
  int node = b * 1024 + threadIdx.x;
  cur[threadIdx.x] = (node < NN) ? offs[node] : 0;
  __syncthreads();
  int r0 = bbase[b], r1 = bbase[b + 1];
  for (int i = r0 + threadIdx.x; i < r1; i += 1024) {
    uint2 u = bsorted[i];
    int p = atomicAdd(&cur[u.x >> 18], 1);
    u.x &= SRCMASK;  // pure src index
    sedge[p] = u;
  }
}

// ============== fused conv0 + mlp0 + l2norm -> h1 bf16 [N,32] ==============
// 2 lanes per node: lane parity q owns x-chunk float4 at +q*4.

__global__ __launch_bounds__(256) void fused0_kernel(
    const float* __restrict__ x, const int* __restrict__ offs,
    const int* __restrict__ cnt, const uint2* __restrict__ sedge,
    const float* __restrict__ W0, const float* __restrict__ b0,
    unsigned short* __restrict__ h1bf) {
  __shared__ float w0t[32][16];  // w0t[j][k] = W0[k*32+j]
  __shared__ float b0s[32];
  int tid = threadIdx.x;
  for (int i = tid; i < 16 * 32; i += 256) {
    int k = i >> 5, j = i & 31;
    w0t[j][k] = W0[i];
  }
  if (tid < 32) b0s[tid] = b0[tid];
  __syncthreads();

  int idx = blockIdx.x * 256 + tid;
  int node = idx >> 1, q = idx & 1;
  if (node >= NN) return;

  int start = offs[node];
  int deg = cnt[node];
  float a0 = 0.f, a1 = 0.f, a2 = 0.f, a3 = 0.f;  // k0 * own x-chunk
  float c0 = 0.f, c1 = 0.f, c2 = 0.f, c3 = 0.f;  // k1 * own x-chunk

  for (int i = 0; i < deg; ++i) {
    uint2 e = sedge[start + i];
    float k0 = bflo(e.y), k1 = bfhi(e.y);
    float4 v = *reinterpret_cast<const float4*>(x + (size_t)e.x * 8 + q * 4);
    a0 += k0 * v.x; a1 += k0 * v.y; a2 += k0 * v.z; a3 += k0 * v.w;
    c0 += k1 * v.x; c1 += k1 * v.y; c2 += k1 * v.z; c3 += k1 * v.w;
  }

  // exchange with partner lane (lane^1) to assemble full h16
  float pa0 = __shfl_xor(a0, 1), pa1 = __shfl_xor(a1, 1);
  float pa2 = __shfl_xor(a2, 1), pa3 = __shfl_xor(a3, 1);
  float pc0 = __shfl_xor(c0, 1), pc1 = __shfl_xor(c1, 1);
  float pc2 = __shfl_xor(c2, 1), pc3 = __shfl_xor(c3, 1);
  bool q0 = (q == 0);
  // h[k]: k0-part of x[0..7] then k1-part of x[0..7]
  float h0 = q0 ? a0 : pa0, h1 = q0 ? a1 : pa1;
  float h2 = q0 ? a2 : pa2, h3 = q0 ? a3 : pa3;
  float h4 = q0 ? pa0 : a0, h5 = q0 ? pa1 : a1;
  float h6 = q0 ? pa2 : a2, h7 = q0 ? pa3 : a3;
  float h8 = q0 ? c0 : pc0, h9 = q0 ? c1 : pc1;
  float h10 = q0 ? c2 : pc2, h11 = q0 ? c3 : pc3;
  float h12 = q0 ? pc0 : c0, h13 = q0 ? pc1 : c1;
  float h14 = q0 ? pc2 : c2, h15 = q0 ? pc3 : c3;

  // each lane computes 16 of the 32 outputs: j in [q*16, q*16+16)
  float o[16];
  float ss = 0.f;
#pragma unroll
  for (int jj = 0; jj < 16; ++jj) {
    int j = q * 16 + jj;
    float acc = b0s[j];
    acc += h0 * w0t[j][0] + h1 * w0t[j][1] + h2 * w0t[j][2] + h3 * w0t[j][3];
    acc += h4 * w0t[j][4] + h5 * w0t[j][5] + h6 * w0t[j][6] + h7 * w0t[j][7];
    acc += h8 * w0t[j][8] + h9 * w0t[j][9] + h10 * w0t[j][10] + h11 * w0t[j][11];
    acc += h12 * w0t[j][12] + h13 * w0t[j][13] + h14 * w0t[j][14] + h15 * w0t[j][15];
    o[jj] = acc;
    ss += acc * acc;
  }
  ss += __shfl_xor(ss, 1);
  float inv = 1.f / fmaxf(sqrtf(ss), 1e-12f);

  uint4* op = reinterpret_cast<uint4*>(h1bf + (size_t)node * 32 + q * 16);
  uint4 u0, u1;
  u0.x = pack2(o[0] * inv, o[1] * inv);  u0.y = pack2(o[2] * inv, o[3] * inv);
  u0.z = pack2(o[4] * inv, o[5] * inv);  u0.w = pack2(o[6] * inv, o[7] * inv);
  u1.x = pack2(o[8] * inv, o[9] * inv);  u1.y = pack2(o[10] * inv, o[11] * inv);
  u1.z = pack2(o[12] * inv, o[13] * inv); u1.w = pack2(o[14] * inv, o[15] * inv);
  op[0] = u0;
  op[1] = u1;
}

// ============== gather1: CSR gather of h1 -> g bf16 [N,64] ==============
// 4 lanes per node: lane q reads h1 chunk [q*8, q*8+8), writes g chunks
// [q*8,+8) (k0) and [32+q*8,+8) (k1).

__global__ __launch_bounds__(256) void gather1_kernel(
    const unsigned short* __restrict__ h1bf, const int* __restrict__ offs,
    const int* __restrict__ cnt, const uint2* __restrict__ sedge,
    unsigned short* __restrict__ gbf) {
  int idx = blockIdx.x * 256 + threadIdx.x;
  int node = idx >> 2, q = idx & 3;
  if (node >= NN) return;
  int start = offs[node];
  int deg = cnt[node];

  float g0[8], g1[8];
#pragma unroll
  for (int k = 0; k < 8; ++k) { g0[k] = 0.f; g1[k] = 0.f; }

  for (int i = 0; i < deg; ++i) {
    uint2 e = sedge[start + i];
    float k0 = bflo(e.y), k1 = bfhi(e.y);
    uint4 u = *reinterpret_cast<const uint4*>(h1bf + (size_t)e.x * 32 + q * 8);
    float v0 = bflo(u.x), v1 = bfhi(u.x);
    float v2 = bflo(u.y), v3 = bfhi(u.y);
    float v4 = bflo(u.z), v5 = bfhi(u.z);
    float v6 = bflo(u.w), v7 = bfhi(u.w);
    g0[0] += k0 * v0; g0[1] += k0 * v1; g0[2] += k0 * v2; g0[3] += k0 * v3;
    g0[4] += k0 * v4; g0[5] += k0 * v5; g0[6] += k0 * v6; g0[7] += k0 * v7;
    g1[0] += k1 * v0; g1[1] += k1 * v1; g1[2] += k1 * v2; g1[3] += k1 * v3;
    g1[4] += k1 * v4; g1[5] += k1 * v5; g1[6] += k1 * v6; g1[7] += k1 * v7;
  }

  uint4 s0, s1;
  s0.x = pack2(g0[0], g0[1]); s0.y = pack2(g0[2], g0[3]);
  s0.z = pack2(g0[4], g0[5]); s0.w = pack2(g0[6], g0[7]);
  s1.x = pack2(g1[0], g1[1]); s1.y = pack2(g1[2], g1[3]);
  s1.z = pack2(g1[4], g1[5]); s1.w = pack2(g1[6], g1[7]);
  *reinterpret_cast<uint4*>(gbf + (size_t)node * 64 + q * 8) = s0;
  *reinterpret_cast<uint4*>(gbf + (size_t)node * 64 + 32 + q * 8) = s1;
}

// ============== mlp1: MFMA 16x16x32_bf16, 16 nodes per wave-tile ==============
// A: row=lane&15, k=(lane>>4)*8+i ; B: col=lane&15, k=(lane>>4)*8+i
// D: col=lane&15, row=(lane>>4)*4+q   [m89-verified]

__global__ __launch_bounds__(256) void mlp1_kernel(
    const unsigned short* __restrict__ gbf,
    const float* __restrict__ W1, const float* __restrict__ b1,
    const float* __restrict__ W2, const float* __restrict__ b2,
    float* __restrict__ out) {
  __shared__ __align__(16) short hlds[4][16][136];
  int tid = threadIdx.x;
  int wave = tid >> 6, lane = tid & 63;
  int lg = lane >> 4;
  int lr = lane & 15;

  bf16x8 w1f[8][2];
#pragma unroll
  for (int n = 0; n < 8; ++n)
#pragma unroll
    for (int ks = 0; ks < 2; ++ks) {
      bf16x8 f;
#pragma unroll
      for (int i = 0; i < 8; ++i)
        f[i] = (short)f2bfu(W1[(size_t)(ks * 32 + lg * 8 + i) * 128 + n * 16 + lr]);
      w1f[n][ks] = f;
    }
  bf16x8 w2f[4][4];
#pragma unroll
  for (int n2 = 0; n2 < 4; ++n2)
#pragma unroll
    for (int ks = 0; ks < 4; ++ks) {
      bf16x8 f;
#pragma unroll
      for (int i = 0; i < 8; ++i)
        f[i] = (short)f2bfu(W2[(size_t)(ks * 32 + lg * 8 + i) * 64 + n2 * 16 + lr]);
      w2f[n2][ks] = f;
    }
  float b1v[8], b2v[4];
#pragma unroll
  for (int n = 0; n < 8; ++n) b1v[n] = b1[n * 16 + lr];
#pragma unroll
  for (int n2 = 0; n2 < 4; ++n2) b2v[n2] = b2[n2 * 16 + lr];

  for (int tile = blockIdx.x * 4 + wave; tile < NT_MLP1; tile += gridDim.x * 4) {
    int base = tile * 16;
    const bf16x8* grow = reinterpret_cast<const bf16x8*>(gbf + (size_t)(base + lr) * 64);
    bf16x8 a1_0 = grow[lg];
    bf16x8 a1_1 = grow[4 + lg];

#pragma unroll
    for (int n = 0; n < 8; ++n) {
      f32x4 acc = {0.f, 0.f, 0.f, 0.f};
      acc = __builtin_amdgcn_mfma_f32_16x16x32_bf16(a1_0, w1f[n][0], acc, 0, 0, 0);
      acc = __builtin_amdgcn_mfma_f32_16x16x32_bf16(a1_1, w1f[n][1], acc, 0, 0, 0);
#pragma unroll
      for (int q = 0; q < 4; ++q) {
        float v = fmaxf(acc[q] + b1v[n], 0.f);
        hlds[wave][lg * 4 + q][n * 16 + lr] = (short)f2bfu(v);
      }
    }

    bf16x8 a2[4];
#pragma unroll
    for (int ks = 0; ks < 4; ++ks)
      a2[ks] = *reinterpret_cast<const bf16x8*>(&hlds[wave][lr][ks * 32 + lg * 8]);
    f32x4 acc2[4];
#pragma unroll
    for (int n2 = 0; n2 < 4; ++n2) {
      f32x4 a = {0.f, 0.f, 0.f, 0.f};
#pragma unroll
      for (int ks = 0; ks < 4; ++ks)
        a = __builtin_amdgcn_mfma_f32_16x16x32_bf16(a2[ks], w2f[n2][ks], a, 0, 0, 0);
      acc2[n2] = a;
    }

#pragma unroll
    for (int q = 0; q < 4; ++q) {
      float s = 0.f;
#pragma unroll
      for (int n2 = 0; n2 < 4; ++n2) {
        float v = acc2[n2][q] + b2v[n2];
        s += v * v;
      }
      s += __shfl_xor(s, 1); s += __shfl_xor(s, 2);
      s += __shfl_xor(s, 4); s += __shfl_xor(s, 8);
      float inv = 1.f / fmaxf(sqrtf(s), 1e-12f);
      size_t rowoff = (size_t)(base + lg * 4 + q) * 64 + lr;
#pragma unroll
      for (int n2 = 0; n2 < 4; ++n2)
        out[rowoff + n2 * 16] = (acc2[n2][q] + b2v[n2]) * inv;
    }
  }
}

// ======================= launch =======================

extern "C" void kernel_launch(void* const* d_in, const int* in_sizes, int n_in,
                              void* d_out, int out_size, void* d_ws, size_t ws_size,
                              hipStream_t stream) {
  const float* x  = (const float*)d_in[0];
  const int* ei   = (const int*)d_in[1];
  const float* kw = (const float*)d_in[2];
  const float* W0 = (const float*)d_in[3];
  const float* b0 = (const float*)d_in[4];
  const float* W1 = (const float*)d_in[5];
  const float* b1 = (const float*)d_in[6];
  const float* W2 = (const float*)d_in[7];
  const float* b2 = (const float*)d_in[8];
  float* out = (float*)d_out;

  const int* src = ei;
  const int* dst = ei + NE;

  // ws layout (8B-aligned chunks), ~66 MB total:
  char* p = (char*)d_ws;
  uint2* bsorted = (uint2*)p;              p += (size_t)NE * 8;          // 25.6 MB
  uint2* sedge   = (uint2*)p;              p += (size_t)NE * 8;          // 25.6 MB
  unsigned short* h1bf = (unsigned short*)p; p += (size_t)NN * 32 * 2;   // 12.8 MB
  int* bhT   = (int*)p;                    p += (size_t)NBUCK * NBLK_A * 4;  // 0.4 MB
  int* btot  = (int*)p;                    p += (size_t)NBUCK * 4;
  int* bbase = (int*)p;                    p += (size_t)(NBUCK + 1) * 4;
  int* cnt   = (int*)p;                    p += (size_t)NN * 4;          // 0.8 MB
  int* offs  = (int*)p;                    p += (size_t)NN * 4;          // 0.8 MB
  int* bsums = (int*)p;                    p += 1024 * 4;
  // gbf reuses bsorted (dead after nplace); NN*64*2 == NE*8 bytes exactly.
  unsigned short* gbf = (unsigned short*)bsorted;

  bhist_kernel<<<NBLK_A, 256, 0, stream>>>(dst, bhT);
  bscan_kernel<<<NBUCK, NBLK_A, 0, stream>>>(bhT, btot);
  bbase_kernel<<<1, 256, 0, stream>>>(btot, bbase);
  bplace_kernel<<<NBLK_A, 256, 0, stream>>>(src, dst, kw, bhT, bbase, bsorted);

  nhist_kernel<<<NBUCK, 1024, 0, stream>>>(bsorted, bbase, cnt);
  scan1_kernel<<<NB_SCAN, 256, 0, stream>>>(cnt, offs, bsums);
  scan2_kernel<<<1, 1024, 0, stream>>>(bsums, NB_SCAN);
  scan3_kernel<<<NB_SCAN, 256, 0, stream>>>(cnt, bsums, offs);
  nplace_kernel<<<NBUCK, 1024, 0, stream>>>(bsorted, bbase, offs, sedge);

  fused0_kernel<<<(2 * NN + 255) / 256, 256, 0, stream>>>(x, offs, cnt, sedge,
                                                          W0, b0, h1bf);
  gather1_kernel<<<(4 * NN + 255) / 256, 256, 0, stream>>>(h1bf, offs, cnt,
                                                           sedge, gbf);
  mlp1_kernel<<<768, 256, 0, stream>>>(gbf, W1, b1, W2, b2, out);
}

// Round 11
// 252.949 us; speedup vs baseline: 1.0017x; 1.0017x over previous
//
#include <hip/hip_runtime.h>

#define NN 200000
#define NE 3200000
#define NB_SCAN 782    // ceil(NN/256) node-scan blocks
#define NBUCK 196      // dst buckets of 1024 nodes (dst>>10)
#define BSHIFT 10
#define BMASK 1023
#define SRCMASK 0x3FFFFu   // src fits in 18 bits (200000 < 2^18)
#define NBLK_A 512     // bucket-pass blocks
#define EPB (NE / NBLK_A)  // 6250 edges per bucket-pass block
#define NT_MLP1 12500  // NN/16 wave-tiles

using bf16x8 = __attribute__((ext_vector_type(8))) short;
using f32x4  = __attribute__((ext_vector_type(4))) float;

__device__ __forceinline__ float bflo(unsigned u) { return __uint_as_float(u << 16); }
__device__ __forceinline__ float bfhi(unsigned u) { return __uint_as_float(u & 0xffff0000u); }
__device__ __forceinline__ unsigned short f2bfu(float f) {
  unsigned u = __float_as_uint(f);
  return (unsigned short)((u + 0x7fffu + ((u >> 16) & 1u)) >> 16);  // RNE
}
__device__ __forceinline__ unsigned pack2(float a, float b) {
  return (unsigned)f2bfu(a) | ((unsigned)f2bfu(b) << 16);
}

// ======================= stage 1: bucket histogram (LDS) =======================

__global__ __launch_bounds__(256) void bhist_kernel(const int* __restrict__ dst,
                                                    int* __restrict__ bhT) {
  __shared__ int h[NBUCK];
  for (int k = threadIdx.x; k < NBUCK; k += 256) h[k] = 0;
  __syncthreads();
  int base = blockIdx.x * EPB;
  for (int i = threadIdx.x; i < EPB; i += 256)
    atomicAdd(&h[dst[base + i] >> BSHIFT], 1);
  __syncthreads();
  for (int k = threadIdx.x; k < NBUCK; k += 256)
    bhT[k * NBLK_A + blockIdx.x] = h[k];
}

// per-bucket exclusive scan over the NBLK_A block entries -> bhT in place, totals
__global__ __launch_bounds__(NBLK_A) void bscan_kernel(int* __restrict__ bhT,
                                                       int* __restrict__ btot) {
  __shared__ int s[NBLK_A];
  int b = blockIdx.x;
  int v = bhT[b * NBLK_A + threadIdx.x];
  s[threadIdx.x] = v;
  __syncthreads();
#pragma unroll
  for (int off = 1; off < NBLK_A; off <<= 1) {
    int t = (threadIdx.x >= off) ? s[threadIdx.x - off] : 0;
    __syncthreads();
    s[threadIdx.x] += t;
    __syncthreads();
  }
  bhT[b * NBLK_A + threadIdx.x] = s[threadIdx.x] - v;  // exclusive
  if (threadIdx.x == NBLK_A - 1) btot[b] = s[NBLK_A - 1];
}

// exclusive scan of btot[NBUCK] -> bbase[NBUCK+1]
__global__ __launch_bounds__(256) void bbase_kernel(const int* __restrict__ btot,
                                                    int* __restrict__ bbase) {
  __shared__ int s[256];
  int v = (threadIdx.x < NBUCK) ? btot[threadIdx.x] : 0;
  s[threadIdx.x] = v;
  __syncthreads();
#pragma unroll
  for (int off = 1; off < 256; off <<= 1) {
    int t = (threadIdx.x >= off) ? s[threadIdx.x - off] : 0;
    __syncthreads();
    s[threadIdx.x] += t;
    __syncthreads();
  }
  if (threadIdx.x < NBUCK) bbase[threadIdx.x] = s[threadIdx.x] - v;
  if (threadIdx.x == NBUCK - 1) bbase[NBUCK] = s[threadIdx.x];
}

// bucket placement: write packed edge {src | dst_lo<<18, kw2} bucket-sorted
__global__ __launch_bounds__(256) void bplace_kernel(
    const int* __restrict__ src, const int* __restrict__ dst,
    const float* __restrict__ kw, const int* __restrict__ bhT,
    const int* __restrict__ bbase, uint2* __restrict__ bsorted) {
  __shared__ int cur[NBUCK];
  for (int k = threadIdx.x; k < NBUCK; k += 256)
    cur[k] = bbase[k] + bhT[k * NBLK_A + blockIdx.x];
  __syncthreads();
  int base = blockIdx.x * EPB;
  for (int i = threadIdx.x; i < EPB; i += 256) {
    int e = base + i;
    int d = dst[e];
    int p = atomicAdd(&cur[d >> BSHIFT], 1);
    uint2 u;
    u.x = (unsigned)src[e] | ((unsigned)(d & BMASK) << 18);
    u.y = pack2(kw[e], kw[NE + e]);
    bsorted[p] = u;
  }
}

// ======================= stage 2: per-node counts (LDS) =======================

__global__ __launch_bounds__(1024) void nhist_kernel(const uint2* __restrict__ bsorted,
                                                     const int* __restrict__ bbase,
                                                     int* __restrict__ cnt) {
  __shared__ int h[1024];
  h[threadIdx.x] = 0;
  __syncthreads();
  int b = blockIdx.x;
  int r0 = bbase[b], r1 = bbase[b + 1];
  for (int i = r0 + threadIdx.x; i < r1; i += 1024)
    atomicAdd(&h[bsorted[i].x >> 18], 1);
  __syncthreads();
  int node = b * 1024 + threadIdx.x;
  if (node < NN) cnt[node] = h[threadIdx.x];
}

// node-level scans (global exclusive offsets)
__global__ __launch_bounds__(256) void scan1_kernel(const int* __restrict__ cnt,
                                                    int* __restrict__ offs,
                                                    int* __restrict__ bsums) {
  __shared__ int s[256];
  int i = blockIdx.x * 256 + threadIdx.x;
  int v = (i < NN) ? cnt[i] : 0;
  s[threadIdx.x] = v;
  __syncthreads();
#pragma unroll
  for (int off = 1; off < 256; off <<= 1) {
    int t = (threadIdx.x >= off) ? s[threadIdx.x - off] : 0;
    __syncthreads();
    s[threadIdx.x] += t;
    __syncthreads();
  }
  if (i < NN) offs[i] = s[threadIdx.x];
  if (threadIdx.x == 255) bsums[blockIdx.x] = s[255];
}

__global__ __launch_bounds__(1024) void scan2_kernel(int* __restrict__ bsums, int nb) {
  __shared__ int s[1024];
  int v = (threadIdx.x < nb) ? bsums[threadIdx.x] : 0;
  s[threadIdx.x] = v;
  __syncthreads();
#pragma unroll
  for (int off = 1; off < 1024; off <<= 1) {
    int t = (threadIdx.x >= off) ? s[threadIdx.x - off] : 0;
    __syncthreads();
    s[threadIdx.x] += t;
    __syncthreads();
  }
  if (threadIdx.x < nb) bsums[threadIdx.x] = s[threadIdx.x] - v;  // exclusive
}

__global__ __launch_bounds__(256) void scan3_kernel(const int* __restrict__ cnt,
                                                    const int* __restrict__ bsums,
                                                    int* __restrict__ offs) {
  int i = blockIdx.x * 256 + threadIdx.x;
  if (i >= NN) return;
  offs[i] = offs[i] - cnt[i] + bsums[blockIdx.x];
}

// final placement within bucket window (L2-resident writes)
__global__ __launch_bounds__(1024) void nplace_kernel(const uint2* __restrict__ bsorted,
                                                      const int* __restrict__ bbase,
                                                      const int* __restrict__ offs,
                                                      uint2* __restrict__ sedge) {
  __shared__ int cur[1024];
  int b = blockIdx.x;
  int node = b * 1024 + threadIdx.x;
  cur[threadIdx.x] = (node < NN) ? offs[node] : 0;
  __syncthreads();
  int r0 = bbase[b], r1 = bbase[b + 1];
  for (int i = r0 + threadIdx.x; i < r1; i += 1024) {
    uint2 u = bsorted[i];
    int p = atomicAdd(&cur[u.x >> 18], 1);
    u.x &= SRCMASK;  // pure src index
    sedge[p] = u;
  }
}

// ============== fused conv0 + mlp0 + l2norm -> h1 bf16 [N,32] ==============
// 2 lanes per node: lane parity q owns x-chunk float4 at +q*4.

__global__ __launch_bounds__(256) void fused0_kernel(
    const float* __restrict__ x, const int* __restrict__ offs,
    const int* __restrict__ cnt, const uint2* __restrict__ sedge,
    const float* __restrict__ W0, const float* __restrict__ b0,
    unsigned short* __restrict__ h1bf) {
  __shared__ float w0t[32][16];  // w0t[j][k] = W0[k*32+j]
  __shared__ float b0s[32];
  int tid = threadIdx.x;
  for (int i = tid; i < 16 * 32; i += 256) {
    int k = i >> 5, j = i & 31;
    w0t[j][k] = W0[i];
  }
  if (tid < 32) b0s[tid] = b0[tid];
  __syncthreads();

  int idx = blockIdx.x * 256 + tid;
  int node = idx >> 1, q = idx & 1;
  if (node >= NN) return;

  int start = offs[node];
  int deg = cnt[node];
  float a0 = 0.f, a1 = 0.f, a2 = 0.f, a3 = 0.f;  // k0 * own x-chunk
  float c0 = 0.f, c1 = 0.f, c2 = 0.f, c3 = 0.f;  // k1 * own x-chunk

  for (int i = 0; i < deg; ++i) {
    uint2 e = sedge[start + i];
    float k0 = bflo(e.y), k1 = bfhi(e.y);
    float4 v = *reinterpret_cast<const float4*>(x + (size_t)e.x * 8 + q * 4);
    a0 += k0 * v.x; a1 += k0 * v.y; a2 += k0 * v.z; a3 += k0 * v.w;
    c0 += k1 * v.x; c1 += k1 * v.y; c2 += k1 * v.z; c3 += k1 * v.w;
  }

  // exchange with partner lane (lane^1) to assemble full h16
  float pa0 = __shfl_xor(a0, 1), pa1 = __shfl_xor(a1, 1);
  float pa2 = __shfl_xor(a2, 1), pa3 = __shfl_xor(a3, 1);
  float pc0 = __shfl_xor(c0, 1), pc1 = __shfl_xor(c1, 1);
  float pc2 = __shfl_xor(c2, 1), pc3 = __shfl_xor(c3, 1);
  bool q0 = (q == 0);
  // h[k]: k0-part of x[0..7] then k1-part of x[0..7]
  float h0 = q0 ? a0 : pa0, h1 = q0 ? a1 : pa1;
  float h2 = q0 ? a2 : pa2, h3 = q0 ? a3 : pa3;
  float h4 = q0 ? pa0 : a0, h5 = q0 ? pa1 : a1;
  float h6 = q0 ? pa2 : a2, h7 = q0 ? pa3 : a3;
  float h8 = q0 ? c0 : pc0, h9 = q0 ? c1 : pc1;
  float h10 = q0 ? c2 : pc2, h11 = q0 ? c3 : pc3;
  float h12 = q0 ? pc0 : c0, h13 = q0 ? pc1 : c1;
  float h14 = q0 ? pc2 : c2, h15 = q0 ? pc3 : c3;

  // each lane computes 16 of the 32 outputs: j in [q*16, q*16+16)
  float o[16];
  float ss = 0.f;
#pragma unroll
  for (int jj = 0; jj < 16; ++jj) {
    int j = q * 16 + jj;
    float acc = b0s[j];
    acc += h0 * w0t[j][0] + h1 * w0t[j][1] + h2 * w0t[j][2] + h3 * w0t[j][3];
    acc += h4 * w0t[j][4] + h5 * w0t[j][5] + h6 * w0t[j][6] + h7 * w0t[j][7];
    acc += h8 * w0t[j][8] + h9 * w0t[j][9] + h10 * w0t[j][10] + h11 * w0t[j][11];
    acc += h12 * w0t[j][12] + h13 * w0t[j][13] + h14 * w0t[j][14] + h15 * w0t[j][15];
    o[jj] = acc;
    ss += acc * acc;
  }
  ss += __shfl_xor(ss, 1);
  float inv = 1.f / fmaxf(sqrtf(ss), 1e-12f);

  uint4* op = reinterpret_cast<uint4*>(h1bf + (size_t)node * 32 + q * 16);
  uint4 u0, u1;
  u0.x = pack2(o[0] * inv, o[1] * inv);  u0.y = pack2(o[2] * inv, o[3] * inv);
  u0.z = pack2(o[4] * inv, o[5] * inv);  u0.w = pack2(o[6] * inv, o[7] * inv);
  u1.x = pack2(o[8] * inv, o[9] * inv);  u1.y = pack2(o[10] * inv, o[11] * inv);
  u1.z = pack2(o[12] * inv, o[13] * inv); u1.w = pack2(o[14] * inv, o[15] * inv);
  op[0] = u0;
  op[1] = u1;
}

// ============== gather1: CSR gather of h1 -> g bf16 [N,64] ==============
// 4 lanes per node: lane q reads h1 chunk [q*8, q*8+8), writes g chunks
// [q*8,+8) (k0) and [32+q*8,+8) (k1).

__global__ __launch_bounds__(256) void gather1_kernel(
    const unsigned short* __restrict__ h1bf, const int* __restrict__ offs,
    const int* __restrict__ cnt, const uint2* __restrict__ sedge,
    unsigned short* __restrict__ gbf) {
  int idx = blockIdx.x * 256 + threadIdx.x;
  int node = idx >> 2, q = idx & 3;
  if (node >= NN) return;
  int start = offs[node];
  int deg = cnt[node];

  float g0[8], g1[8];
#pragma unroll
  for (int k = 0; k < 8; ++k) { g0[k] = 0.f; g1[k] = 0.f; }

  for (int i = 0; i < deg; ++i) {
    uint2 e = sedge[start + i];
    float k0 = bflo(e.y), k1 = bfhi(e.y);
    uint4 u = *reinterpret_cast<const uint4*>(h1bf + (size_t)e.x * 32 + q * 8);
    float v0 = bflo(u.x), v1 = bfhi(u.x);
    float v2 = bflo(u.y), v3 = bfhi(u.y);
    float v4 = bflo(u.z), v5 = bfhi(u.z);
    float v6 = bflo(u.w), v7 = bfhi(u.w);
    g0[0] += k0 * v0; g0[1] += k0 * v1; g0[2] += k0 * v2; g0[3] += k0 * v3;
    g0[4] += k0 * v4; g0[5] += k0 * v5; g0[6] += k0 * v6; g0[7] += k0 * v7;
    g1[0] += k1 * v0; g1[1] += k1 * v1; g1[2] += k1 * v2; g1[3] += k1 * v3;
    g1[4] += k1 * v4; g1[5] += k1 * v5; g1[6] += k1 * v6; g1[7] += k1 * v7;
  }

  uint4 s0, s1;
  s0.x = pack2(g0[0], g0[1]); s0.y = pack2(g0[2], g0[3]);
  s0.z = pack2(g0[4], g0[5]); s0.w = pack2(g0[6], g0[7]);
  s1.x = pack2(g1[0], g1[1]); s1.y = pack2(g1[2], g1[3]);
  s1.z = pack2(g1[4], g1[5]); s1.w = pack2(g1[6], g1[7]);
  *reinterpret_cast<uint4*>(gbf + (size_t)node * 64 + q * 8) = s0;
  *reinterpret_cast<uint4*>(gbf + (size_t)node * 64 + 32 + q * 8) = s1;
}

// ============== mlp1: MFMA 16x16x32_bf16, 16 nodes per wave-tile ==============
// A: row=lane&15, k=(lane>>4)*8+i ; B: col=lane&15, k=(lane>>4)*8+i
// D: col=lane&15, row=(lane>>4)*4+q   [m89-verified]

__global__ __launch_bounds__(256) void mlp1_kernel(
    const unsigned short* __restrict__ gbf,
    const float* __restrict__ W1, const float* __restrict__ b1,
    const float* __restrict__ W2, const float* __restrict__ b2,
    float* __restrict__ out) {
  __shared__ __align__(16) short hlds[4][16][136];
  int tid = threadIdx.x;
  int wave = tid >> 6, lane = tid & 63;
  int lg = lane >> 4;
  int lr = lane & 15;

  bf16x8 w1f[8][2];
#pragma unroll
  for (int n = 0; n < 8; ++n)
#pragma unroll
    for (int ks = 0; ks < 2; ++ks) {
      bf16x8 f;
#pragma unroll
      for (int i = 0; i < 8; ++i)
        f[i] = (short)f2bfu(W1[(size_t)(ks * 32 + lg * 8 + i) * 128 + n * 16 + lr]);
      w1f[n][ks] = f;
    }
  bf16x8 w2f[4][4];
#pragma unroll
  for (int n2 = 0; n2 < 4; ++n2)
#pragma unroll
    for (int ks = 0; ks < 4; ++ks) {
      bf16x8 f;
#pragma unroll
      for (int i = 0; i < 8; ++i)
        f[i] = (short)f2bfu(W2[(size_t)(ks * 32 + lg * 8 + i) * 64 + n2 * 16 + lr]);
      w2f[n2][ks] = f;
    }
  float b1v[8], b2v[4];
#pragma unroll
  for (int n = 0; n < 8; ++n) b1v[n] = b1[n * 16 + lr];
#pragma unroll
  for (int n2 = 0; n2 < 4; ++n2) b2v[n2] = b2[n2 * 16 + lr];

  for (int tile = blockIdx.x * 4 + wave; tile < NT_MLP1; tile += gridDim.x * 4) {
    int base = tile * 16;
    const bf16x8* grow = reinterpret_cast<const bf16x8*>(gbf + (size_t)(base + lr) * 64);
    bf16x8 a1_0 = grow[lg];
    bf16x8 a1_1 = grow[4 + lg];

#pragma unroll
    for (int n = 0; n < 8; ++n) {
      f32x4 acc = {0.f, 0.f, 0.f, 0.f};
      acc = __builtin_amdgcn_mfma_f32_16x16x32_bf16(a1_0, w1f[n][0], acc, 0, 0, 0);
      acc = __builtin_amdgcn_mfma_f32_16x16x32_bf16(a1_1, w1f[n][1], acc, 0, 0, 0);
#pragma unroll
      for (int q = 0; q < 4; ++q) {
        float v = fmaxf(acc[q] + b1v[n], 0.f);
        hlds[wave][lg * 4 + q][n * 16 + lr] = (short)f2bfu(v);
      }
    }

    bf16x8 a2[4];
#pragma unroll
    for (int ks = 0; ks < 4; ++ks)
      a2[ks] = *reinterpret_cast<const bf16x8*>(&hlds[wave][lr][ks * 32 + lg * 8]);
    f32x4 acc2[4];
#pragma unroll
    for (int n2 = 0; n2 < 4; ++n2) {
      f32x4 a = {0.f, 0.f, 0.f, 0.f};
#pragma unroll
      for (int ks = 0; ks < 4; ++ks)
        a = __builtin_amdgcn_mfma_f32_16x16x32_bf16(a2[ks], w2f[n2][ks], a, 0, 0, 0);
      acc2[n2] = a;
    }

#pragma unroll
    for (int q = 0; q < 4; ++q) {
      float s = 0.f;
#pragma unroll
      for (int n2 = 0; n2 < 4; ++n2) {
        float v = acc2[n2][q] + b2v[n2];
        s += v * v;
      }
      s += __shfl_xor(s, 1); s += __shfl_xor(s, 2);
      s += __shfl_xor(s, 4); s += __shfl_xor(s, 8);
      float inv = 1.f / fmaxf(sqrtf(s), 1e-12f);
      size_t rowoff = (size_t)(base + lg * 4 + q) * 64 + lr;
#pragma unroll
      for (int n2 = 0; n2 < 4; ++n2)
        out[rowoff + n2 * 16] = (acc2[n2][q] + b2v[n2]) * inv;
    }
  }
}

// ======================= launch =======================

extern "C" void kernel_launch(void* const* d_in, const int* in_sizes, int n_in,
                              void* d_out, int out_size, void* d_ws, size_t ws_size,
                              hipStream_t stream) {
  const float* x  = (const float*)d_in[0];
  const int* ei   = (const int*)d_in[1];
  const float* kw = (const float*)d_in[2];
  const float* W0 = (const float*)d_in[3];
  const float* b0 = (const float*)d_in[4];
  const float* W1 = (const float*)d_in[5];
  const float* b1 = (const float*)d_in[6];
  const float* W2 = (const float*)d_in[7];
  const float* b2 = (const float*)d_in[8];
  float* out = (float*)d_out;

  const int* src = ei;
  const int* dst = ei + NE;

  // ws layout (8B-aligned chunks), ~66 MB total:
  char* p = (char*)d_ws;
  uint2* bsorted = (uint2*)p;              p += (size_t)NE * 8;          // 25.6 MB
  uint2* sedge   = (uint2*)p;              p += (size_t)NE * 8;          // 25.6 MB
  unsigned short* h1bf = (unsigned short*)p; p += (size_t)NN * 32 * 2;   // 12.8 MB
  int* bhT   = (int*)p;                    p += (size_t)NBUCK * NBLK_A * 4;  // 0.4 MB
  int* btot  = (int*)p;                    p += (size_t)NBUCK * 4;
  int* bbase = (int*)p;                    p += (size_t)(NBUCK + 1) * 4;
  int* cnt   = (int*)p;                    p += (size_t)NN * 4;          // 0.8 MB
  int* offs  = (int*)p;                    p += (size_t)NN * 4;          // 0.8 MB
  int* bsums = (int*)p;                    p += 1024 * 4;
  // gbf reuses bsorted (dead after nplace); NN*64*2 == NE*8 bytes exactly.
  unsigned short* gbf = (unsigned short*)bsorted;

  bhist_kernel<<<NBLK_A, 256, 0, stream>>>(dst, bhT);
  bscan_kernel<<<NBUCK, NBLK_A, 0, stream>>>(bhT, btot);
  bbase_kernel<<<1, 256, 0, stream>>>(btot, bbase);
  bplace_kernel<<<NBLK_A, 256, 0, stream>>>(src, dst, kw, bhT, bbase, bsorted);

  nhist_kernel<<<NBUCK, 1024, 0, stream>>>(bsorted, bbase, cnt);
  scan1_kernel<<<NB_SCAN, 256, 0, stream>>>(cnt, offs, bsums);
  scan2_kernel<<<1, 1024, 0, stream>>>(bsums, NB_SCAN);
  scan3_kernel<<<NB_SCAN, 256, 0, stream>>>(cnt, bsums, offs);
  nplace_kernel<<<NBUCK, 1024, 0, stream>>>(bsorted, bbase, offs, sedge);

  fused0_kernel<<<(2 * NN + 255) / 256, 256, 0, stream>>>(x, offs, cnt, sedge,
                                                          W0, b0, h1bf);
  gather1_kernel<<<(4 * NN + 255) / 256, 256, 0, stream>>>(h1bf, offs, cnt,
                                                           sedge, gbf);
  mlp1_kernel<<<768, 256, 0, stream>>>(gbf, W1, b1, W2, b2, out);
}

// Round 12
// 243.974 us; speedup vs baseline: 1.0385x; 1.0368x over previous
//
#include <hip/hip_runtime.h>

#define NN 200000
#define NE 3200000
#define NB_SCAN 782    // ceil(NN/256) node-scan blocks
#define NBUCK 196      // dst buckets of 1024 nodes (dst>>10)
#define BSHIFT 10
#define BMASK 1023
#define SRCMASK 0x3FFFFu   // src fits in 18 bits (200000 < 2^18)
#define NBLK_A 512     // bucket-pass blocks
#define EPB (NE / NBLK_A)  // 6250 edges per bucket-pass block
#define NT_MLP1 12500  // NN/16 wave-tiles
#define NPASS 13       // src slices: src>>14, 200000/16384 = 12.2 -> 0..12
#define EMAX 18        // max edges per nplace thread (bucket<=18432; mean 16384, sd~128)

using bf16x8 = __attribute__((ext_vector_type(8))) short;
using f32x4  = __attribute__((ext_vector_type(4))) float;

__device__ __forceinline__ float bflo(unsigned u) { return __uint_as_float(u << 16); }
__device__ __forceinline__ float bfhi(unsigned u) { return __uint_as_float(u & 0xffff0000u); }
__device__ __forceinline__ unsigned short f2bfu(float f) {
  unsigned u = __float_as_uint(f);
  return (unsigned short)((u + 0x7fffu + ((u >> 16) & 1u)) >> 16);  // RNE
}
__device__ __forceinline__ unsigned pack2(float a, float b) {
  return (unsigned)f2bfu(a) | ((unsigned)f2bfu(b) << 16);
}

// ======================= stage 1: bucket histogram (LDS) =======================

__global__ __launch_bounds__(256) void bhist_kernel(const int* __restrict__ dst,
                                                    int* __restrict__ bhT) {
  __shared__ int h[NBUCK];
  for (int k = threadIdx.x; k < NBUCK; k += 256) h[k] = 0;
  __syncthreads();
  int base = blockIdx.x * EPB;
  for (int i = threadIdx.x; i < EPB; i += 256)
    atomicAdd(&h[dst[base + i] >> BSHIFT], 1);
  __syncthreads();
  for (int k = threadIdx.x; k < NBUCK; k += 256)
    bhT[k * NBLK_A + blockIdx.x] = h[k];
}

// per-bucket exclusive scan over the NBLK_A block entries -> bhT in place, totals
__global__ __launch_bounds__(NBLK_A) void bscan_kernel(int* __restrict__ bhT,
                                                       int* __restrict__ btot) {
  __shared__ int s[NBLK_A];
  int b = blockIdx.x;
  int v = bhT[b * NBLK_A + threadIdx.x];
  s[threadIdx.x] = v;
  __syncthreads();
#pragma unroll
  for (int off = 1; off < NBLK_A; off <<= 1) {
    int t = (threadIdx.x >= off) ? s[threadIdx.x - off] : 0;
    __syncthreads();
    s[threadIdx.x] += t;
    __syncthreads();
  }
  bhT[b * NBLK_A + threadIdx.x] = s[threadIdx.x] - v;  // exclusive
  if (threadIdx.x == NBLK_A - 1) btot[b] = s[NBLK_A - 1];
}

// exclusive scan of btot[NBUCK] -> bbase[NBUCK+1]
__global__ __launch_bounds__(256) void bbase_kernel(const int* __restrict__ btot,
                                                    int* __restrict__ bbase) {
  __shared__ int s[256];
  int v = (threadIdx.x < NBUCK) ? btot[threadIdx.x] : 0;
  s[threadIdx.x] = v;
  __syncthreads();
#pragma unroll
  for (int off = 1; off < 256; off <<= 1) {
    int t = (threadIdx.x >= off) ? s[threadIdx.x - off] : 0;
    __syncthreads();
    s[threadIdx.x] += t;
    __syncthreads();
  }
  if (threadIdx.x < NBUCK) bbase[threadIdx.x] = s[threadIdx.x] - v;
  if (threadIdx.x == NBUCK - 1) bbase[NBUCK] = s[threadIdx.x];
}

// bucket placement: write packed edge {src | dst_lo<<18, kw2} bucket-sorted
__global__ __launch_bounds__(256) void bplace_kernel(
    const int* __restrict__ src, const int* __restrict__ dst,
    const float* __restrict__ kw, const int* __restrict__ bhT,
    const int* __restrict__ bbase, uint2* __restrict__ bsorted) {
  __shared__ int cur[NBUCK];
  for (int k = threadIdx.x; k < NBUCK; k += 256)
    cur[k] = bbase[k] + bhT[k * NBLK_A + blockIdx.x];
  __syncthreads();
  int base = blockIdx.x * EPB;
  for (int i = threadIdx.x; i < EPB; i += 256) {
    int e = base + i;
    int d = dst[e];
    int p = atomicAdd(&cur[d >> BSHIFT], 1);
    uint2 u;
    u.x = (unsigned)src[e] | ((unsigned)(d & BMASK) << 18);
    u.y = pack2(kw[e], kw[NE + e]);
    bsorted[p] = u;
  }
}

// ======================= stage 2: per-node counts (LDS) =======================

__global__ __launch_bounds__(1024) void nhist_kernel(const uint2* __restrict__ bsorted,
                                                     const int* __restrict__ bbase,
                                                     int* __restrict__ cnt) {
  __shared__ int h[1024];
  h[threadIdx.x] = 0;
  __syncthreads();
  int b = blockIdx.x;
  int r0 = bbase[b], r1 = bbase[b + 1];
  for (int i = r0 + threadIdx.x; i < r1; i += 1024)
    atomicAdd(&h[bsorted[i].x >> 18], 1);
  __syncthreads();
  int node = b * 1024 + threadIdx.x;
  if (node < NN) cnt[node] = h[threadIdx.x];
}

// node-level scans (global exclusive offsets)
__global__ __launch_bounds__(256) void scan1_kernel(const int* __restrict__ cnt,
                                                    int* __restrict__ offs,
                                                    int* __restrict__ bsums) {
  __shared__ int s[256];
  int i = blockIdx.x * 256 + threadIdx.x;
  int v = (i < NN) ? cnt[i] : 0;
  s[threadIdx.x] = v;
  __syncthreads();
#pragma unroll
  for (int off = 1; off < 256; off <<= 1) {
    int t = (threadIdx.x >= off) ? s[threadIdx.x - off] : 0;
    __syncthreads();
    s[threadIdx.x] += t;
    __syncthreads();
  }
  if (i < NN) offs[i] = s[threadIdx.x];
  if (threadIdx.x == 255) bsums[blockIdx.x] = s[255];
}

__global__ __launch_bounds__(1024) void scan2_kernel(int* __restrict__ bsums, int nb) {
  __shared__ int s[1024];
  int v = (threadIdx.x < nb) ? bsums[threadIdx.x] : 0;
  s[threadIdx.x] = v;
  __syncthreads();
#pragma unroll
  for (int off = 1; off < 1024; off <<= 1) {
    int t = (threadIdx.x >= off) ? s[threadIdx.x - off] : 0;
    __syncthreads();
    s[threadIdx.x] += t;
    __syncthreads();
  }
  if (threadIdx.x < nb) bsums[threadIdx.x] = s[threadIdx.x] - v;  // exclusive
}

__global__ __launch_bounds__(256) void scan3_kernel(const int* __restrict__ cnt,
                                                    const int* __restrict__ bsums,
                                                    int* __restrict__ offs) {
  int i = blockIdx.x * 256 + threadIdx.x;
  if (i >= NN) return;
  offs[i] = offs[i] - cnt[i] + bsums[blockIdx.x];
}

// final placement within bucket window, src-slice-ordered per node list.
// Each thread register-caches its <=EMAX edges (statically indexed), then NPASS
// predicated passes place edges in ascending src>>14 slice; barrier between
// passes keeps per-node slice ordering. gather1's concurrent h1 working set
// becomes ~2 slices (~2MB) -> per-XCD L2-resident.
__global__ __launch_bounds__(1024) void nplace_kernel(const uint2* __restrict__ bsorted,
                                                      const int* __restrict__ bbase,
                                                      const int* __restrict__ offs,
                                                      uint2* __restrict__ sedge) {
  __shared__ int cur[1024];
  int b = blockIdx.x;
  int node = b * 1024 + threadIdx.x;
  cur[threadIdx.x] = (node < NN) ? offs[node] : 0;
  __syncthreads();
  int r0 = bbase[b], r1 = bbase[b + 1];
  int i0 = r0 + threadIdx.x;

  uint2 e[EMAX];
#pragma unroll
  for (int j = 0; j < EMAX; ++j) {
    int i = i0 + j * 1024;
    if (i < r1) e[j] = bsorted[i];
  }

  for (int p = 0; p < NPASS; ++p) {
#pragma unroll
    for (int j = 0; j < EMAX; ++j) {
      int i = i0 + j * 1024;
      if (i < r1) {
        unsigned srcv = e[j].x & SRCMASK;
        if ((int)(srcv >> 14) == p) {
          int pos = atomicAdd(&cur[e[j].x >> 18], 1);
          uint2 w; w.x = srcv; w.y = e[j].y;
          sedge[pos] = w;
        }
      }
    }
    __syncthreads();
  }
  // overflow safety (bucket > EMAX*1024 edges; statistically never)
  for (int i = i0 + EMAX * 1024; i < r1; i += 1024) {
    uint2 u = bsorted[i];
    int pos = atomicAdd(&cur[u.x >> 18], 1);
    u.x &= SRCMASK;
    sedge[pos] = u;
  }
}

// ============== x -> bf16 table (3.2 MB, per-XCD L2-resident) ==============

__global__ __launch_bounds__(256) void xcvt_kernel(const float* __restrict__ x,
                                                   unsigned short* __restrict__ xbf) {
  int i = blockIdx.x * 256 + threadIdx.x;
  if (i >= NN) return;
  const float4* xp = reinterpret_cast<const float4*>(x + (size_t)i * 8);
  float4 a = xp[0], b = xp[1];
  uint4 u;
  u.x = pack2(a.x, a.y); u.y = pack2(a.z, a.w);
  u.z = pack2(b.x, b.y); u.w = pack2(b.z, b.w);
  *reinterpret_cast<uint4*>(xbf + (size_t)i * 8) = u;
}

// ============== fused conv0 + mlp0 + l2norm -> h1 bf16 [N,32] ==============
// 1 thread per node; per edge one 16B bf16 x-row load (L2-resident table).

__global__ __launch_bounds__(256) void fused0_kernel(
    const unsigned short* __restrict__ xbf, const int* __restrict__ offs,
    const int* __restrict__ cnt, const uint2* __restrict__ sedge,
    const float* __restrict__ W0, const float* __restrict__ b0,
    unsigned short* __restrict__ h1bf) {
  __shared__ float w0t[32][16];  // w0t[j][k] = W0[k*32+j]
  __shared__ float b0s[32];
  int tid = threadIdx.x;
  for (int i = tid; i < 16 * 32; i += 256) {
    int k = i >> 5, j = i & 31;
    w0t[j][k] = W0[i];
  }
  if (tid < 32) b0s[tid] = b0[tid];
  __syncthreads();

  int node = blockIdx.x * 256 + tid;
  if (node >= NN) return;

  int start = offs[node];
  int deg = cnt[node];
  float h16[16];
#pragma unroll
  for (int k = 0; k < 16; ++k) h16[k] = 0.f;

  for (int i = 0; i < deg; ++i) {
    uint2 e = sedge[start + i];
    float k0 = bflo(e.y), k1 = bfhi(e.y);
    uint4 u = *reinterpret_cast<const uint4*>(xbf + (size_t)e.x * 8);
    float v0 = bflo(u.x), v1 = bfhi(u.x);
    float v2 = bflo(u.y), v3 = bfhi(u.y);
    float v4 = bflo(u.z), v5 = bfhi(u.z);
    float v6 = bflo(u.w), v7 = bfhi(u.w);
    h16[0] += k0 * v0; h16[1] += k0 * v1; h16[2] += k0 * v2; h16[3] += k0 * v3;
    h16[4] += k0 * v4; h16[5] += k0 * v5; h16[6] += k0 * v6; h16[7] += k0 * v7;
    h16[8]  += k1 * v0; h16[9]  += k1 * v1; h16[10] += k1 * v2; h16[11] += k1 * v3;
    h16[12] += k1 * v4; h16[13] += k1 * v5; h16[14] += k1 * v6; h16[15] += k1 * v7;
  }

  float o[32];
  float ss = 0.f;
#pragma unroll
  for (int j = 0; j < 32; ++j) {
    float acc = b0s[j];
#pragma unroll
    for (int k = 0; k < 16; ++k) acc += h16[k] * w0t[j][k];
    o[j] = acc;
    ss += acc * acc;
  }
  float inv = 1.f / fmaxf(sqrtf(ss), 1e-12f);
  uint4* op = reinterpret_cast<uint4*>(h1bf + (size_t)node * 32);
#pragma unroll
  for (int c = 0; c < 4; ++c) {
    uint4 u;
    u.x = pack2(o[c * 8 + 0] * inv, o[c * 8 + 1] * inv);
    u.y = pack2(o[c * 8 + 2] * inv, o[c * 8 + 3] * inv);
    u.z = pack2(o[c * 8 + 4] * inv, o[c * 8 + 5] * inv);
    u.w = pack2(o[c * 8 + 6] * inv, o[c * 8 + 7] * inv);
    op[c] = u;
  }
}

// ============== gather1: CSR gather of h1 -> g bf16 [N,64] ==============
// 4 lanes per node: lane q reads h1 chunk [q*8, q*8+8), writes g chunks
// [q*8,+8) (k0) and [32+q*8,+8) (k1). Edge lists are src-slice-ordered.

__global__ __launch_bounds__(256) void gather1_kernel(
    const unsigned short* __restrict__ h1bf, const int* __restrict__ offs,
    const int* __restrict__ cnt, const uint2* __restrict__ sedge,
    unsigned short* __restrict__ gbf) {
  int idx = blockIdx.x * 256 + threadIdx.x;
  int node = idx >> 2, q = idx & 3;
  if (node >= NN) return;
  int start = offs[node];
  int deg = cnt[node];

  float g0[8], g1[8];
#pragma unroll
  for (int k = 0; k < 8; ++k) { g0[k] = 0.f; g1[k] = 0.f; }

  for (int i = 0; i < deg; ++i) {
    uint2 e = sedge[start + i];
    float k0 = bflo(e.y), k1 = bfhi(e.y);
    uint4 u = *reinterpret_cast<const uint4*>(h1bf + (size_t)e.x * 32 + q * 8);
    float v0 = bflo(u.x), v1 = bfhi(u.x);
    float v2 = bflo(u.y), v3 = bfhi(u.y);
    float v4 = bflo(u.z), v5 = bfhi(u.z);
    float v6 = bflo(u.w), v7 = bfhi(u.w);
    g0[0] += k0 * v0; g0[1] += k0 * v1; g0[2] += k0 * v2; g0[3] += k0 * v3;
    g0[4] += k0 * v4; g0[5] += k0 * v5; g0[6] += k0 * v6; g0[7] += k0 * v7;
    g1[0] += k1 * v0; g1[1] += k1 * v1; g1[2] += k1 * v2; g1[3] += k1 * v3;
    g1[4] += k1 * v4; g1[5] += k1 * v5; g1[6] += k1 * v6; g1[7] += k1 * v7;
  }

  uint4 s0, s1;
  s0.x = pack2(g0[0], g0[1]); s0.y = pack2(g0[2], g0[3]);
  s0.z = pack2(g0[4], g0[5]); s0.w = pack2(g0[6], g0[7]);
  s1.x = pack2(g1[0], g1[1]); s1.y = pack2(g1[2], g1[3]);
  s1.z = pack2(g1[4], g1[5]); s1.w = pack2(g1[6], g1[7]);
  *reinterpret_cast<uint4*>(gbf + (size_t)node * 64 + q * 8) = s0;
  *reinterpret_cast<uint4*>(gbf + (size_t)node * 64 + 32 + q * 8) = s1;
}

// ============== mlp1: MFMA 16x16x32_bf16, 16 nodes per wave-tile ==============
// A: row=lane&15, k=(lane>>4)*8+i ; B: col=lane&15, k=(lane>>4)*8+i
// D: col=lane&15, row=(lane>>4)*4+q   [m89-verified]

__global__ __launch_bounds__(256) void mlp1_kernel(
    const unsigned short* __restrict__ gbf,
    const float* __restrict__ W1, const float* __restrict__ b1,
    const float* __restrict__ W2, const float* __restrict__ b2,
    float* __restrict__ out) {
  __shared__ __align__(16) short hlds[4][16][136];
  int tid = threadIdx.x;
  int wave = tid >> 6, lane = tid & 63;
  int lg = lane >> 4;
  int lr = lane & 15;

  bf16x8 w1f[8][2];
#pragma unroll
  for (int n = 0; n < 8; ++n)
#pragma unroll
    for (int ks = 0; ks < 2; ++ks) {
      bf16x8 f;
#pragma unroll
      for (int i = 0; i < 8; ++i)
        f[i] = (short)f2bfu(W1[(size_t)(ks * 32 + lg * 8 + i) * 128 + n * 16 + lr]);
      w1f[n][ks] = f;
    }
  bf16x8 w2f[4][4];
#pragma unroll
  for (int n2 = 0; n2 < 4; ++n2)
#pragma unroll
    for (int ks = 0; ks < 4; ++ks) {
      bf16x8 f;
#pragma unroll
      for (int i = 0; i < 8; ++i)
        f[i] = (short)f2bfu(W2[(size_t)(ks * 32 + lg * 8 + i) * 64 + n2 * 16 + lr]);
      w2f[n2][ks] = f;
    }
  float b1v[8], b2v[4];
#pragma unroll
  for (int n = 0; n < 8; ++n) b1v[n] = b1[n * 16 + lr];
#pragma unroll
  for (int n2 = 0; n2 < 4; ++n2) b2v[n2] = b2[n2 * 16 + lr];

  for (int tile = blockIdx.x * 4 + wave; tile < NT_MLP1; tile += gridDim.x * 4) {
    int base = tile * 16;
    const bf16x8* grow = reinterpret_cast<const bf16x8*>(gbf + (size_t)(base + lr) * 64);
    bf16x8 a1_0 = grow[lg];
    bf16x8 a1_1 = grow[4 + lg];

#pragma unroll
    for (int n = 0; n < 8; ++n) {
      f32x4 acc = {0.f, 0.f, 0.f, 0.f};
      acc = __builtin_amdgcn_mfma_f32_16x16x32_bf16(a1_0, w1f[n][0], acc, 0, 0, 0);
      acc = __builtin_amdgcn_mfma_f32_16x16x32_bf16(a1_1, w1f[n][1], acc, 0, 0, 0);
#pragma unroll
      for (int q = 0; q < 4; ++q) {
        float v = fmaxf(acc[q] + b1v[n], 0.f);
        hlds[wave][lg * 4 + q][n * 16 + lr] = (short)f2bfu(v);
      }
    }

    bf16x8 a2[4];
#pragma unroll
    for (int ks = 0; ks < 4; ++ks)
      a2[ks] = *reinterpret_cast<const bf16x8*>(&hlds[wave][lr][ks * 32 + lg * 8]);
    f32x4 acc2[4];
#pragma unroll
    for (int n2 = 0; n2 < 4; ++n2) {
      f32x4 a = {0.f, 0.f, 0.f, 0.f};
#pragma unroll
      for (int ks = 0; ks < 4; ++ks)
        a = __builtin_amdgcn_mfma_f32_16x16x32_bf16(a2[ks], w2f[n2][ks], a, 0, 0, 0);
      acc2[n2] = a;
    }

#pragma unroll
    for (int q = 0; q < 4; ++q) {
      float s = 0.f;
#pragma unroll
      for (int n2 = 0; n2 < 4; ++n2) {
        float v = acc2[n2][q] + b2v[n2];
        s += v * v;
      }
      s += __shfl_xor(s, 1); s += __shfl_xor(s, 2);
      s += __shfl_xor(s, 4); s += __shfl_xor(s, 8);
      float inv = 1.f / fmaxf(sqrtf(s), 1e-12f);
      size_t rowoff = (size_t)(base + lg * 4 + q) * 64 + lr;
#pragma unroll
      for (int n2 = 0; n2 < 4; ++n2)
        out[rowoff + n2 * 16] = (acc2[n2][q] + b2v[n2]) * inv;
    }
  }
}

// ======================= launch =======================

extern "C" void kernel_launch(void* const* d_in, const int* in_sizes, int n_in,
                              void* d_out, int out_size, void* d_ws, size_t ws_size,
                              hipStream_t stream) {
  const float* x  = (const float*)d_in[0];
  const int* ei   = (const int*)d_in[1];
  const float* kw = (const float*)d_in[2];
  const float* W0 = (const float*)d_in[3];
  const float* b0 = (const float*)d_in[4];
  const float* W1 = (const float*)d_in[5];
  const float* b1 = (const float*)d_in[6];
  const float* W2 = (const float*)d_in[7];
  const float* b2 = (const float*)d_in[8];
  float* out = (float*)d_out;

  const int* src = ei;
  const int* dst = ei + NE;

  // ws layout (8B-aligned chunks), ~70 MB total (harness ws >= 77 MB, R1-proven):
  char* p = (char*)d_ws;
  uint2* bsorted = (uint2*)p;              p += (size_t)NE * 8;          // 25.6 MB
  uint2* sedge   = (uint2*)p;              p += (size_t)NE * 8;          // 25.6 MB
  unsigned short* h1bf = (unsigned short*)p; p += (size_t)NN * 32 * 2;   // 12.8 MB
  unsigned short* xbf  = (unsigned short*)p; p += (size_t)NN * 8 * 2;    // 3.2 MB
  int* bhT   = (int*)p;                    p += (size_t)NBUCK * NBLK_A * 4;  // 0.4 MB
  int* btot  = (int*)p;                    p += (size_t)NBUCK * 4;
  int* bbase = (int*)p;                    p += (size_t)(NBUCK + 1) * 4;
  int* cnt   = (int*)p;                    p += (size_t)NN * 4;          // 0.8 MB
  int* offs  = (int*)p;                    p += (size_t)NN * 4;          // 0.8 MB
  int* bsums = (int*)p;                    p += 1024 * 4;
  // gbf reuses bsorted (dead after nplace); NN*64*2 == NE*8 bytes exactly.
  unsigned short* gbf = (unsigned short*)bsorted;

  xcvt_kernel<<<NB_SCAN, 256, 0, stream>>>(x, xbf);

  bhist_kernel<<<NBLK_A, 256, 0, stream>>>(dst, bhT);
  bscan_kernel<<<NBUCK, NBLK_A, 0, stream>>>(bhT, btot);
  bbase_kernel<<<1, 256, 0, stream>>>(btot, bbase);
  bplace_kernel<<<NBLK_A, 256, 0, stream>>>(src, dst, kw, bhT, bbase, bsorted);

  nhist_kernel<<<NBUCK, 1024, 0, stream>>>(bsorted, bbase, cnt);
  scan1_kernel<<<NB_SCAN, 256, 0, stream>>>(cnt, offs, bsums);
  scan2_kernel<<<1, 1024, 0, stream>>>(bsums, NB_SCAN);
  scan3_kernel<<<NB_SCAN, 256, 0, stream>>>(cnt, bsums, offs);
  nplace_kernel<<<NBUCK, 1024, 0, stream>>>(bsorted, bbase, offs, sedge);

  fused0_kernel<<<NB_SCAN, 256, 0, stream>>>(xbf, offs, cnt, sedge, W0, b0, h1bf);
  gather1_kernel<<<(4 * NN + 255) / 256, 256, 0, stream>>>(h1bf, offs, cnt,
                                                           sedge, gbf);
  mlp1_kernel<<<768, 256, 0, stream>>>(gbf, W1, b1, W2, b2, out);
}